// Round 2
// baseline (1274.530 us; speedup 1.0000x reference)
//
#include <hip/hip_runtime.h>

#define N_NODES 100000
#define N_EDGES 1000000
#define HID 64
#define SCAN_B 1024
#define SCAN_NB ((N_NODES + SCAN_B - 1) / SCAN_B)   // 98

// x[n] = node_emb[z[n]]  (16 threads per node, float4 each)
__global__ __launch_bounds__(256) void gather_kernel(
    const float* __restrict__ node_emb, const int* __restrict__ z,
    float* __restrict__ x)
{
    int t = blockIdx.x * 256 + threadIdx.x;
    int n = t >> 4, c = t & 15;
    if (n >= N_NODES) return;
    int zi = z[n];
    float4 v = ((const float4*)(node_emb + (size_t)zi * HID))[c];
    ((float4*)(x + (size_t)n * HID))[c] = v;
}

// offs[dst[e]] += 1  (degree histogram; offs pre-zeroed)
__global__ __launch_bounds__(256) void hist_kernel(
    const int* __restrict__ dst, int* __restrict__ offs)
{
    int e = blockIdx.x * 256 + threadIdx.x;
    if (e < N_EDGES) atomicAdd(&offs[dst[e]], 1);
}

// ---- multi-block exclusive scan (3 phases) ----
// Phase 1: per-block exclusive scan in place, block totals to bsum.
__global__ __launch_bounds__(1024) void scan1_kernel(
    int* __restrict__ offs, int* __restrict__ bsum)
{
    __shared__ int wsum[16];
    int tid = threadIdx.x, lane = tid & 63, wid = tid >> 6;
    int i = blockIdx.x * SCAN_B + tid;
    int v = (i < N_NODES) ? offs[i] : 0;
    int s = v;
#pragma unroll
    for (int d = 1; d < 64; d <<= 1) {
        int t = __shfl_up(s, (unsigned)d, 64);
        if (lane >= d) s += t;
    }
    if (lane == 63) wsum[wid] = s;
    __syncthreads();
    if (wid == 0) {
        int w = (lane < 16) ? wsum[lane] : 0;
#pragma unroll
        for (int d = 1; d < 16; d <<= 1) {
            int t = __shfl_up(w, (unsigned)d, 64);
            if (lane >= d) w += t;
        }
        if (lane < 16) wsum[lane] = w;
    }
    __syncthreads();
    int woff = (wid == 0) ? 0 : wsum[wid - 1];
    if (i < N_NODES) offs[i] = woff + s - v;     // block-local exclusive
    if (tid == 1023) bsum[blockIdx.x] = wsum[15]; // block total
}

// Phase 2: exclusive scan of the 98 block totals (1 block, 2 waves).
__global__ __launch_bounds__(128) void scan2_kernel(int* __restrict__ bsum)
{
    __shared__ int ws[2];
    int tid = threadIdx.x, lane = tid & 63, wid = tid >> 6;
    int v = (tid < SCAN_NB) ? bsum[tid] : 0;
    int s = v;
#pragma unroll
    for (int d = 1; d < 64; d <<= 1) {
        int t = __shfl_up(s, (unsigned)d, 64);
        if (lane >= d) s += t;
    }
    if (lane == 63) ws[wid] = s;
    __syncthreads();
    int add = (wid == 1) ? ws[0] : 0;
    if (tid < SCAN_NB) bsum[tid] = add + s - v;  // exclusive
}

// Phase 3: add block offset. Published with atomicExch so the downstream
// atomicAdd cursor RMW (fill_kernel, possibly other XCD) never RMWs a
// stale value: atomic->atomic stays at the coherent point.
__global__ __launch_bounds__(1024) void scan3_kernel(
    int* __restrict__ offs, const int* __restrict__ bsum)
{
    int i = blockIdx.x * SCAN_B + threadIdx.x;
    if (i < N_NODES) {
        int v = offs[i] + bsum[blockIdx.x];
        atomicExch(&offs[i], v);
    }
}

// eid2[slot] = (e, src[e]); offs becomes END offsets after this
// (start[n] = offs[n-1] afterwards, start[0] = 0).
__global__ __launch_bounds__(256) void fill_kernel(
    const int* __restrict__ src, const int* __restrict__ dst,
    int* __restrict__ offs, int2* __restrict__ eid2)
{
    int e = blockIdx.x * 256 + threadIdx.x;
    if (e < N_EDGES) {
        int d = dst[e];
        int pos = atomicAdd(&offs[d], 1);
        eid2[pos] = make_int2(e, src[e]);
    }
}

// Canonicalize each node's slot range to ascending edge-id order so the
// aggregation sum order is launch-invariant (fill's atomic cursor order is
// not). Wave per node, 64-lane bitonic sort, INT_MAX padding. Degrees are
// ~Poisson(10); P(deg>64) ~ 1e-40 — such nodes are left in cursor order.
__global__ __launch_bounds__(256) void sort_kernel(
    const int* __restrict__ offs, int2* __restrict__ eid2)
{
    int gt = blockIdx.x * 256 + threadIdx.x;
    int n = gt >> 6;
    int lane = threadIdx.x & 63;
    if (n >= N_NODES) return;                 // wave-uniform
    int start = (n == 0) ? 0 : offs[n - 1];
    int end = offs[n];
    int deg = end - start;
    if (deg <= 1 || deg > 64) return;         // wave-uniform
    int ke = 0x7fffffff, vs = 0;
    if (lane < deg) { int2 t = eid2[start + lane]; ke = t.x; vs = t.y; }
#pragma unroll
    for (int k = 2; k <= 64; k <<= 1) {
        for (int j = k >> 1; j > 0; j >>= 1) {
            int partner = lane ^ j;
            int ke2 = __shfl(ke, partner, 64);
            int vs2 = __shfl(vs, partner, 64);
            bool up = ((lane & k) == 0);
            bool takemin = ((lane < partner) == up);
            bool sw = takemin ? (ke2 < ke) : (ke2 > ke);
            if (sw) { ke = ke2; vs = vs2; }
        }
    }
    if (lane < deg) eid2[start + lane] = make_int2(ke, vs);
}

// W2T_all[m][j][c] = W2[m][c][j]  (so mlp layer-2 reads contiguous rows
// with wave-uniform addresses -> scalar loads, zero LDS)
__global__ __launch_bounds__(256) void transposeW2_kernel(
    const float* __restrict__ W2, float* __restrict__ W2T)
{
    int t = blockIdx.x * 256 + threadIdx.x;
    if (t < 3 * HID * HID) {
        int m = t / (HID * HID), idx = t % (HID * HID);
        int r = idx >> 6, col = idx & 63;
        W2T[m * HID * HID + col * HID + r] = W2[t];
    }
}

// Wave-per-node aggregation: lane c = channel c. No atomics.
// agg[n][c] = sum over incoming edges of relu(x[src][c] + ea[e][c])
// 2-edge software pipeline: 2-deep eid2 prefetch + independent partial
// sums, so each latency window covers two edges instead of one.
__global__ __launch_bounds__(256) void agg_kernel(
    const float* __restrict__ x, const float* __restrict__ ea,
    const int2* __restrict__ eid2, const int* __restrict__ offs,
    float* __restrict__ agg)
{
    int gt = blockIdx.x * 256 + threadIdx.x;
    int n = gt >> 6;
    int c = threadIdx.x & 63;
    if (n >= N_NODES) return;
    int nu = __builtin_amdgcn_readfirstlane(n);   // force SGPR edge-list walk
    int start = (nu == 0) ? 0 : offs[nu - 1];
    int end = offs[nu];
    float acc0 = 0.f, acc1 = 0.f;
    int i = start;
    int2 e0 = make_int2(0, 0), e1 = make_int2(0, 0);
    if (i < end) e0 = eid2[i];
    if (i + 1 < end) e1 = eid2[i + 1];
    while (i + 2 <= end) {
        int2 a = e0, b = e1;
        if (i + 2 < end) e0 = eid2[i + 2];        // prefetch pair
        if (i + 3 < end) e1 = eid2[i + 3];
        float xa = x[(size_t)a.y * HID + c];
        float pa = ea[(size_t)a.x * HID + c];
        float xb = x[(size_t)b.y * HID + c];
        float pb = ea[(size_t)b.x * HID + c];
        acc0 += fmaxf(xa + pa, 0.f);
        acc1 += fmaxf(xb + pb, 0.f);
        i += 2;
    }
    if (i < end) {                                // odd remainder: e0 = eid2[i]
        float m = x[(size_t)e0.y * HID + c] + ea[(size_t)e0.x * HID + c];
        acc0 += fmaxf(m, 0.f);
    }
    agg[(size_t)n * HID + c] = acc0 + acc1;
}

// Per-node MLP, outer-product form, in-place on x. NO LDS: weight rows are
// read with wave-uniform addresses from global (W1 rows, pre-transposed W2T
// rows, b1/b2) -> compiler emits s_load through the scalar/constant cache,
// keeping the LDS pipe idle and FMA fed from SGPR operands. 64-thread
// blocks (1563 blocks) for CU load balance; no staging barrier needed.
// o = (relu?)(W2 @ relu(W1 @ (agg+x) + b1) + b2) + x
__global__ __launch_bounds__(64) void mlp_kernel(
    const float* __restrict__ agg,
    const float* __restrict__ W1, const float* __restrict__ b1,
    const float* __restrict__ W2T, const float* __restrict__ b2,
    float* __restrict__ x, int last_relu)
{
    int n = blockIdx.x * 64 + threadIdx.x;
    if (n >= N_NODES) return;

    const float4* ap = (const float4*)(agg + (size_t)n * HID);
    const float4* xp = (const float4*)(x + (size_t)n * HID);

    float in[HID];
#pragma unroll
    for (int c = 0; c < 16; ++c) {
        float4 a = ap[c], b = xp[c];
        in[4*c+0] = a.x + b.x;
        in[4*c+1] = a.y + b.y;
        in[4*c+2] = a.z + b.z;
        in[4*c+3] = a.w + b.w;
    }

    float o[HID];
    const float4* b2p = (const float4*)b2;
#pragma unroll
    for (int c = 0; c < 16; ++c) {
        float4 b = b2p[c];
        o[4*c+0] = b.x; o[4*c+1] = b.y; o[4*c+2] = b.z; o[4*c+3] = b.w;
    }

    for (int j = 0; j < HID; ++j) {
        const float4* w1p = (const float4*)(W1 + j * HID);   // uniform -> s_load
        float a0 = 0.f, a1 = 0.f, a2 = 0.f, a3 = 0.f;  // break dep chain 4-way
#pragma unroll
        for (int c = 0; c < 16; c += 4) {
            float4 wa = w1p[c+0], wb = w1p[c+1], wc = w1p[c+2], wd = w1p[c+3];
            a0 += in[4*c+ 0]*wa.x + in[4*c+ 1]*wa.y + in[4*c+ 2]*wa.z + in[4*c+ 3]*wa.w;
            a1 += in[4*c+ 4]*wb.x + in[4*c+ 5]*wb.y + in[4*c+ 6]*wb.z + in[4*c+ 7]*wb.w;
            a2 += in[4*c+ 8]*wc.x + in[4*c+ 9]*wc.y + in[4*c+10]*wc.z + in[4*c+11]*wc.w;
            a3 += in[4*c+12]*wd.x + in[4*c+13]*wd.y + in[4*c+14]*wd.z + in[4*c+15]*wd.w;
        }
        float h = fmaxf((a0 + a1) + (a2 + a3) + b1[j], 0.f);
        const float4* w2p = (const float4*)(W2T + j * HID);  // uniform -> s_load
#pragma unroll
        for (int c = 0; c < 16; ++c) {
            float4 w = w2p[c];
            o[4*c+0] += h * w.x;
            o[4*c+1] += h * w.y;
            o[4*c+2] += h * w.z;
            o[4*c+3] += h * w.w;
        }
    }

    float* orow = x + (size_t)n * HID;   // in-place: row-private
#pragma unroll
    for (int c = 0; c < 16; ++c) {
        float4 xv = xp[c];
        float4 r;
        r.x = (last_relu ? fmaxf(o[4*c+0], 0.f) : o[4*c+0]) + xv.x;
        r.y = (last_relu ? fmaxf(o[4*c+1], 0.f) : o[4*c+1]) + xv.y;
        r.z = (last_relu ? fmaxf(o[4*c+2], 0.f) : o[4*c+2]) + xv.z;
        r.w = (last_relu ? fmaxf(o[4*c+3], 0.f) : o[4*c+3]) + xv.w;
        ((float4*)orow)[c] = r;
    }
}

extern "C" void kernel_launch(void* const* d_in, const int* in_sizes, int n_in,
                              void* d_out, int out_size, void* d_ws, size_t ws_size,
                              hipStream_t stream) {
    const float* node_emb = (const float*)d_in[0];
    const float* W1 = (const float*)d_in[1];
    const float* b1 = (const float*)d_in[2];
    const float* W2 = (const float*)d_in[3];
    const float* b2 = (const float*)d_in[4];
    const float* ea = (const float*)d_in[5];
    const int* z = (const int*)d_in[6];
    const int* ei = (const int*)d_in[7];
    const int* src = ei;            // edge_index[0] = message sender
    const int* dst = ei + N_EDGES;  // edge_index[1] = aggregation target

    float* x = (float*)d_out;                       // node features live here
    float* agg = (float*)d_ws;                      // 25.6 MB
    int2* eid2 = (int2*)((char*)d_ws + (size_t)N_NODES * HID * sizeof(float)); // 8 MB
    int* offs = (int*)(eid2 + N_EDGES);             // 0.4 MB
    int* bsum = offs + N_NODES;                     // 98 ints (padded to 128)
    float* W2T = (float*)(bsum + 128);              // 3 x 16 KB, 16B-aligned

    const int eb = (N_EDGES + 255) / 256;            // 3907
    const int gather_blocks = (N_NODES * 16) / 256;  // 6250
    const int nodewave_blocks = (N_NODES * 64) / 256; // 25000
    const int mlp_blocks = (N_NODES + 63) / 64;      // 1563
    const int tw2_blocks = (3 * HID * HID + 255) / 256; // 48

    // ---- CSR build (once, reused by all 3 convs) ----
    hipMemsetAsync(offs, 0, N_NODES * sizeof(int), stream);
    gather_kernel<<<gather_blocks, 256, 0, stream>>>(node_emb, z, x);
    hist_kernel<<<eb, 256, 0, stream>>>(dst, offs);
    scan1_kernel<<<SCAN_NB, SCAN_B, 0, stream>>>(offs, bsum);
    scan2_kernel<<<1, 128, 0, stream>>>(bsum);
    scan3_kernel<<<SCAN_NB, SCAN_B, 0, stream>>>(offs, bsum);
    fill_kernel<<<eb, 256, 0, stream>>>(src, dst, offs, eid2);
    sort_kernel<<<nodewave_blocks, 256, 0, stream>>>(offs, eid2);
    transposeW2_kernel<<<tw2_blocks, 256, 0, stream>>>(W2, W2T);

    // ---- 3 convs, x updated in place in d_out ----
    for (int conv = 0; conv < 3; ++conv) {
        agg_kernel<<<nodewave_blocks, 256, 0, stream>>>(x, ea, eid2, offs, agg);
        mlp_kernel<<<mlp_blocks, 64, 0, stream>>>(
            agg, W1 + conv * HID * HID, b1 + conv * HID,
            W2T + conv * HID * HID, b2 + conv * HID,
            x, conv < 2 ? 1 : 0);
    }
}

// Round 4
// 1080.049 us; speedup vs baseline: 1.1801x; 1.1801x over previous
//
#include <hip/hip_runtime.h>

#define N_NODES 100000
#define N_EDGES 1000000
#define HID 64
#define SCAN_B 1024
#define SCAN_NB ((N_NODES + SCAN_B - 1) / SCAN_B)   // 98

// x[n] = node_emb[z[n]]  (16 threads per node, float4 each)
__global__ __launch_bounds__(256) void gather_kernel(
    const float* __restrict__ node_emb, const int* __restrict__ z,
    float* __restrict__ x)
{
    int t = blockIdx.x * 256 + threadIdx.x;
    int n = t >> 4, c = t & 15;
    if (n >= N_NODES) return;
    int zi = z[n];
    float4 v = ((const float4*)(node_emb + (size_t)zi * HID))[c];
    ((float4*)(x + (size_t)n * HID))[c] = v;
}

// offs[dst[e]] += 1  (degree histogram; offs pre-zeroed)
__global__ __launch_bounds__(256) void hist_kernel(
    const int* __restrict__ dst, int* __restrict__ offs)
{
    int e = blockIdx.x * 256 + threadIdx.x;
    if (e < N_EDGES) atomicAdd(&offs[dst[e]], 1);
}

// ---- multi-block exclusive scan (3 phases) ----
// Phase 1: per-block exclusive scan in place, block totals to bsum.
__global__ __launch_bounds__(1024) void scan1_kernel(
    int* __restrict__ offs, int* __restrict__ bsum)
{
    __shared__ int wsum[16];
    int tid = threadIdx.x, lane = tid & 63, wid = tid >> 6;
    int i = blockIdx.x * SCAN_B + tid;
    int v = (i < N_NODES) ? offs[i] : 0;
    int s = v;
#pragma unroll
    for (int d = 1; d < 64; d <<= 1) {
        int t = __shfl_up(s, (unsigned)d, 64);
        if (lane >= d) s += t;
    }
    if (lane == 63) wsum[wid] = s;
    __syncthreads();
    if (wid == 0) {
        int w = (lane < 16) ? wsum[lane] : 0;
#pragma unroll
        for (int d = 1; d < 16; d <<= 1) {
            int t = __shfl_up(w, (unsigned)d, 64);
            if (lane >= d) w += t;
        }
        if (lane < 16) wsum[lane] = w;
    }
    __syncthreads();
    int woff = (wid == 0) ? 0 : wsum[wid - 1];
    if (i < N_NODES) offs[i] = woff + s - v;     // block-local exclusive
    if (tid == 1023) bsum[blockIdx.x] = wsum[15]; // block total
}

// Phase 2: exclusive scan of the 98 block totals (1 block, 2 waves).
__global__ __launch_bounds__(128) void scan2_kernel(int* __restrict__ bsum)
{
    __shared__ int ws[2];
    int tid = threadIdx.x, lane = tid & 63, wid = tid >> 6;
    int v = (tid < SCAN_NB) ? bsum[tid] : 0;
    int s = v;
#pragma unroll
    for (int d = 1; d < 64; d <<= 1) {
        int t = __shfl_up(s, (unsigned)d, 64);
        if (lane >= d) s += t;
    }
    if (lane == 63) ws[wid] = s;
    __syncthreads();
    int add = (wid == 1) ? ws[0] : 0;
    if (tid < SCAN_NB) bsum[tid] = add + s - v;  // exclusive
}

// Phase 3: add block offset. Published with atomicExch so the downstream
// atomicAdd cursor RMW (fill_kernel, possibly other XCD) never RMWs a
// stale value: atomic->atomic stays at the coherent point.
__global__ __launch_bounds__(1024) void scan3_kernel(
    int* __restrict__ offs, const int* __restrict__ bsum)
{
    int i = blockIdx.x * SCAN_B + threadIdx.x;
    if (i < N_NODES) {
        int v = offs[i] + bsum[blockIdx.x];
        atomicExch(&offs[i], v);
    }
}

// eid2[slot] = (e, src[e]); offs becomes END offsets after this
// (start[n] = offs[n-1] afterwards, start[0] = 0).
__global__ __launch_bounds__(256) void fill_kernel(
    const int* __restrict__ src, const int* __restrict__ dst,
    int* __restrict__ offs, int2* __restrict__ eid2)
{
    int e = blockIdx.x * 256 + threadIdx.x;
    if (e < N_EDGES) {
        int d = dst[e];
        int pos = atomicAdd(&offs[d], 1);
        eid2[pos] = make_int2(e, src[e]);
    }
}

// Canonicalize each node's slot range to ascending edge-id order so the
// aggregation sum order is launch-invariant (fill's atomic cursor order is
// not). Wave per node, 64-lane bitonic sort, INT_MAX padding. Degrees are
// ~Poisson(10); P(deg>64) ~ 1e-40 — such nodes are left in cursor order.
__global__ __launch_bounds__(256) void sort_kernel(
    const int* __restrict__ offs, int2* __restrict__ eid2)
{
    int gt = blockIdx.x * 256 + threadIdx.x;
    int n = gt >> 6;
    int lane = threadIdx.x & 63;
    if (n >= N_NODES) return;                 // wave-uniform
    int start = (n == 0) ? 0 : offs[n - 1];
    int end = offs[n];
    int deg = end - start;
    if (deg <= 1 || deg > 64) return;         // wave-uniform
    int ke = 0x7fffffff, vs = 0;
    if (lane < deg) { int2 t = eid2[start + lane]; ke = t.x; vs = t.y; }
#pragma unroll
    for (int k = 2; k <= 64; k <<= 1) {
        for (int j = k >> 1; j > 0; j >>= 1) {
            int partner = lane ^ j;
            int ke2 = __shfl(ke, partner, 64);
            int vs2 = __shfl(vs, partner, 64);
            bool up = ((lane & k) == 0);
            bool takemin = ((lane < partner) == up);
            bool sw = takemin ? (ke2 < ke) : (ke2 > ke);
            if (sw) { ke = ke2; vs = vs2; }
        }
    }
    if (lane < deg) eid2[start + lane] = make_int2(ke, vs);
}

// Permute edge_attr into CSR slot order (once; conv-invariant) so all 3
// agg passes read it SEQUENTIALLY instead of 256B-random. Also extract
// the compact src array so agg never touches eid2 again.
// 16 threads per slot, float4 each.
__global__ __launch_bounds__(256) void permute_kernel(
    const float* __restrict__ ea, const int2* __restrict__ eid2,
    float* __restrict__ eap, int* __restrict__ srcs)
{
    int t = blockIdx.x * 256 + threadIdx.x;
    int slot = t >> 4, c = t & 15;
    if (slot >= N_EDGES) return;
    int2 p = eid2[slot];                       // (edge id, src) — same line, 16 lanes
    float4 v = ((const float4*)(ea + (size_t)p.x * HID))[c];
    ((float4*)(eap + (size_t)slot * HID))[c] = v;
    if (c == 0) srcs[slot] = p.y;
}

// Wave-per-node aggregation: lane c = channel c. No atomics.
// agg[n][c] = sum over slots of relu(x[srcs[slot]][c] + eap[slot][c])
// eap reads are sequential (permuted); x reads hit L3 (25.6 MB resident).
// 2-edge software pipeline on the src indices.
__global__ __launch_bounds__(256) void agg_kernel(
    const float* __restrict__ x, const float* __restrict__ eap,
    const int* __restrict__ srcs, const int* __restrict__ offs,
    float* __restrict__ agg)
{
    int gt = blockIdx.x * 256 + threadIdx.x;
    int n = gt >> 6;
    int c = threadIdx.x & 63;
    if (n >= N_NODES) return;
    int nu = __builtin_amdgcn_readfirstlane(n);   // force SGPR edge-list walk
    int start = (nu == 0) ? 0 : offs[nu - 1];
    int end = offs[nu];
    float acc0 = 0.f, acc1 = 0.f;
    int i = start;
    int s0 = 0, s1 = 0;
    if (i < end) s0 = srcs[i];
    if (i + 1 < end) s1 = srcs[i + 1];
    while (i + 2 <= end) {
        int a = s0, b = s1;
        if (i + 2 < end) s0 = srcs[i + 2];        // prefetch pair
        if (i + 3 < end) s1 = srcs[i + 3];
        float xa = x[(size_t)a * HID + c];
        float pa = eap[(size_t)i * HID + c];
        float xb = x[(size_t)b * HID + c];
        float pb = eap[(size_t)(i + 1) * HID + c];
        acc0 += fmaxf(xa + pa, 0.f);
        acc1 += fmaxf(xb + pb, 0.f);
        i += 2;
    }
    if (i < end) {                                // odd remainder
        float m = x[(size_t)s0 * HID + c] + eap[(size_t)i * HID + c];
        acc0 += fmaxf(m, 0.f);
    }
    agg[(size_t)n * HID + c] = acc0 + acc1;
}

// Per-node MLP, outer-product form, weights staged in LDS, in-place on x.
// (Reverted to the LDS form: the global-weight variant was latency-bound,
//  202 µs vs ~55 µs — VALUBusy 11.9%, weight-load dep chain per j.)
// o = (relu?)(W2 @ relu(W1 @ (agg+x) + b1) + b2) + x
__global__ __launch_bounds__(256, 2) void mlp_kernel(
    const float* __restrict__ agg,
    const float* __restrict__ W1, const float* __restrict__ b1,
    const float* __restrict__ W2, const float* __restrict__ b2,
    float* __restrict__ x, int last_relu)
{
    __shared__ float sW1[HID * HID];
    __shared__ float sW2T[HID * HID];
    __shared__ float sb1[HID];
    int tid = threadIdx.x;
    for (int idx = tid; idx < HID * HID; idx += 256) {
        sW1[idx] = W1[idx];
        int r = idx >> 6, col = idx & 63;
        sW2T[col * HID + r] = W2[idx];   // transpose so layer-2 reads rows
    }
    if (tid < HID) sb1[tid] = b1[tid];
    __syncthreads();

    int n = blockIdx.x * 256 + tid;
    if (n >= N_NODES) return;

    const float4* ap = (const float4*)(agg + (size_t)n * HID);
    const float4* xp = (const float4*)(x + (size_t)n * HID);

    float in[HID];
#pragma unroll
    for (int c = 0; c < 16; ++c) {
        float4 a = ap[c], b = xp[c];
        in[4*c+0] = a.x + b.x;
        in[4*c+1] = a.y + b.y;
        in[4*c+2] = a.z + b.z;
        in[4*c+3] = a.w + b.w;
    }

    float o[HID];
    const float4* b2p = (const float4*)b2;
#pragma unroll
    for (int c = 0; c < 16; ++c) {
        float4 b = b2p[c];
        o[4*c+0] = b.x; o[4*c+1] = b.y; o[4*c+2] = b.z; o[4*c+3] = b.w;
    }

    for (int j = 0; j < HID; ++j) {
        const float4* w1p = (const float4*)(sW1 + j * HID);
        float a0 = 0.f, a1 = 0.f, a2 = 0.f, a3 = 0.f;  // break dep chain 4-way
#pragma unroll
        for (int c = 0; c < 16; c += 4) {
            float4 wa = w1p[c+0], wb = w1p[c+1], wc = w1p[c+2], wd = w1p[c+3];
            a0 += in[4*c+ 0]*wa.x + in[4*c+ 1]*wa.y + in[4*c+ 2]*wa.z + in[4*c+ 3]*wa.w;
            a1 += in[4*c+ 4]*wb.x + in[4*c+ 5]*wb.y + in[4*c+ 6]*wb.z + in[4*c+ 7]*wb.w;
            a2 += in[4*c+ 8]*wc.x + in[4*c+ 9]*wc.y + in[4*c+10]*wc.z + in[4*c+11]*wc.w;
            a3 += in[4*c+12]*wd.x + in[4*c+13]*wd.y + in[4*c+14]*wd.z + in[4*c+15]*wd.w;
        }
        float h = fmaxf((a0 + a1) + (a2 + a3) + sb1[j], 0.f);
        const float4* w2p = (const float4*)(sW2T + j * HID);
#pragma unroll
        for (int c = 0; c < 16; ++c) {
            float4 w = w2p[c];
            o[4*c+0] += h * w.x;
            o[4*c+1] += h * w.y;
            o[4*c+2] += h * w.z;
            o[4*c+3] += h * w.w;
        }
    }

    float* orow = x + (size_t)n * HID;   // in-place: row-private
#pragma unroll
    for (int c = 0; c < 16; ++c) {
        float4 xv = xp[c];
        float4 r;
        r.x = (last_relu ? fmaxf(o[4*c+0], 0.f) : o[4*c+0]) + xv.x;
        r.y = (last_relu ? fmaxf(o[4*c+1], 0.f) : o[4*c+1]) + xv.y;
        r.z = (last_relu ? fmaxf(o[4*c+2], 0.f) : o[4*c+2]) + xv.z;
        r.w = (last_relu ? fmaxf(o[4*c+3], 0.f) : o[4*c+3]) + xv.w;
        ((float4*)orow)[c] = r;
    }
}

extern "C" void kernel_launch(void* const* d_in, const int* in_sizes, int n_in,
                              void* d_out, int out_size, void* d_ws, size_t ws_size,
                              hipStream_t stream) {
    const float* node_emb = (const float*)d_in[0];
    const float* W1 = (const float*)d_in[1];
    const float* b1 = (const float*)d_in[2];
    const float* W2 = (const float*)d_in[3];
    const float* b2 = (const float*)d_in[4];
    const float* ea = (const float*)d_in[5];
    const int* z = (const int*)d_in[6];
    const int* ei = (const int*)d_in[7];
    const int* src = ei;            // edge_index[0] = message sender
    const int* dst = ei + N_EDGES;  // edge_index[1] = aggregation target

    float* x = (float*)d_out;                       // node features live here
    // workspace layout (~294 MB of the 1 GB ws):
    float* eap = (float*)d_ws;                               // 256 MB (slot-ordered edge_attr)
    float* agg = eap + (size_t)N_EDGES * HID;                // 25.6 MB
    int2* eid2 = (int2*)(agg + (size_t)N_NODES * HID);       // 8 MB
    int* offs = (int*)(eid2 + N_EDGES);                      // 0.4 MB
    int* bsum = offs + N_NODES;                              // 98 ints (pad 128)
    int* srcs = bsum + 128;                                  // 4 MB

    const int eb = (N_EDGES + 255) / 256;            // 3907
    const int gather_blocks = (N_NODES * 16) / 256;  // 6250
    const int nodewave_blocks = (N_NODES * 64) / 256; // 25000
    const int perm_blocks = (N_EDGES * 16) / 256;    // 62500
    const int mlp_blocks = (N_NODES + 255) / 256;    // 391

    // ---- CSR build (once, reused by all 3 convs) ----
    hipMemsetAsync(offs, 0, N_NODES * sizeof(int), stream);
    gather_kernel<<<gather_blocks, 256, 0, stream>>>(node_emb, z, x);
    hist_kernel<<<eb, 256, 0, stream>>>(dst, offs);
    scan1_kernel<<<SCAN_NB, SCAN_B, 0, stream>>>(offs, bsum);
    scan2_kernel<<<1, 128, 0, stream>>>(bsum);
    scan3_kernel<<<SCAN_NB, SCAN_B, 0, stream>>>(offs, bsum);
    fill_kernel<<<eb, 256, 0, stream>>>(src, dst, offs, eid2);
    sort_kernel<<<nodewave_blocks, 256, 0, stream>>>(offs, eid2);
    permute_kernel<<<perm_blocks, 256, 0, stream>>>(ea, eid2, eap, srcs);

    // ---- 3 convs, x updated in place in d_out ----
    for (int conv = 0; conv < 3; ++conv) {
        agg_kernel<<<nodewave_blocks, 256, 0, stream>>>(x, eap, srcs, offs, agg);
        mlp_kernel<<<mlp_blocks, 256, 0, stream>>>(
            agg, W1 + conv * HID * HID, b1 + conv * HID,
            W2 + conv * HID * HID, b2 + conv * HID,
            x, conv < 2 ? 1 : 0);
    }
}

// Round 5
// 1066.271 us; speedup vs baseline: 1.1953x; 1.0129x over previous
//
#include <hip/hip_runtime.h>

#define N_NODES 100000
#define N_EDGES 1000000
#define HID 64
#define SCAN_B 1024
#define SCAN_NB ((N_NODES + SCAN_B - 1) / SCAN_B)   // 98

// x[n] = node_emb[z[n]]  (16 threads per node, float4 each)
__global__ __launch_bounds__(256) void gather_kernel(
    const float* __restrict__ node_emb, const int* __restrict__ z,
    float* __restrict__ x)
{
    int t = blockIdx.x * 256 + threadIdx.x;
    int n = t >> 4, c = t & 15;
    if (n >= N_NODES) return;
    int zi = z[n];
    float4 v = ((const float4*)(node_emb + (size_t)zi * HID))[c];
    ((float4*)(x + (size_t)n * HID))[c] = v;
}

// offs[dst[e]] += 1  (degree histogram; offs pre-zeroed)
__global__ __launch_bounds__(256) void hist_kernel(
    const int* __restrict__ dst, int* __restrict__ offs)
{
    int e = blockIdx.x * 256 + threadIdx.x;
    if (e < N_EDGES) atomicAdd(&offs[dst[e]], 1);
}

// ---- multi-block exclusive scan (3 phases) ----
// Phase 1: per-block exclusive scan in place, block totals to bsum.
__global__ __launch_bounds__(1024) void scan1_kernel(
    int* __restrict__ offs, int* __restrict__ bsum)
{
    __shared__ int wsum[16];
    int tid = threadIdx.x, lane = tid & 63, wid = tid >> 6;
    int i = blockIdx.x * SCAN_B + tid;
    int v = (i < N_NODES) ? offs[i] : 0;
    int s = v;
#pragma unroll
    for (int d = 1; d < 64; d <<= 1) {
        int t = __shfl_up(s, (unsigned)d, 64);
        if (lane >= d) s += t;
    }
    if (lane == 63) wsum[wid] = s;
    __syncthreads();
    if (wid == 0) {
        int w = (lane < 16) ? wsum[lane] : 0;
#pragma unroll
        for (int d = 1; d < 16; d <<= 1) {
            int t = __shfl_up(w, (unsigned)d, 64);
            if (lane >= d) w += t;
        }
        if (lane < 16) wsum[lane] = w;
    }
    __syncthreads();
    int woff = (wid == 0) ? 0 : wsum[wid - 1];
    if (i < N_NODES) offs[i] = woff + s - v;     // block-local exclusive
    if (tid == 1023) bsum[blockIdx.x] = wsum[15]; // block total
}

// Phase 2: exclusive scan of the 98 block totals (1 block, 2 waves).
__global__ __launch_bounds__(128) void scan2_kernel(int* __restrict__ bsum)
{
    __shared__ int ws[2];
    int tid = threadIdx.x, lane = tid & 63, wid = tid >> 6;
    int v = (tid < SCAN_NB) ? bsum[tid] : 0;
    int s = v;
#pragma unroll
    for (int d = 1; d < 64; d <<= 1) {
        int t = __shfl_up(s, (unsigned)d, 64);
        if (lane >= d) s += t;
    }
    if (lane == 63) ws[wid] = s;
    __syncthreads();
    int add = (wid == 1) ? ws[0] : 0;
    if (tid < SCAN_NB) bsum[tid] = add + s - v;  // exclusive
}

// Phase 3: add block offset. Published with atomicExch so the downstream
// atomicAdd cursor RMW (fill_kernel, possibly other XCD) never RMWs a
// stale value: atomic->atomic stays at the coherent point.
__global__ __launch_bounds__(1024) void scan3_kernel(
    int* __restrict__ offs, const int* __restrict__ bsum)
{
    int i = blockIdx.x * SCAN_B + threadIdx.x;
    if (i < N_NODES) {
        int v = offs[i] + bsum[blockIdx.x];
        atomicExch(&offs[i], v);
    }
}

// eid2[slot] = (e, src[e]); offs becomes END offsets after this
// (start[n] = offs[n-1] afterwards, start[0] = 0).
__global__ __launch_bounds__(256) void fill_kernel(
    const int* __restrict__ src, const int* __restrict__ dst,
    int* __restrict__ offs, int2* __restrict__ eid2)
{
    int e = blockIdx.x * 256 + threadIdx.x;
    if (e < N_EDGES) {
        int d = dst[e];
        int pos = atomicAdd(&offs[d], 1);
        eid2[pos] = make_int2(e, src[e]);
    }
}

// Canonicalize each node's slot range to ascending edge-id order so the
// aggregation sum order is launch-invariant (fill's atomic cursor order is
// not). Wave per node, 64-lane bitonic sort, INT_MAX padding. Degrees are
// ~Poisson(10); P(deg>64) ~ 1e-40 — such nodes are left in cursor order.
__global__ __launch_bounds__(256) void sort_kernel(
    const int* __restrict__ offs, int2* __restrict__ eid2)
{
    int gt = blockIdx.x * 256 + threadIdx.x;
    int n = gt >> 6;
    int lane = threadIdx.x & 63;
    if (n >= N_NODES) return;                 // wave-uniform
    int start = (n == 0) ? 0 : offs[n - 1];
    int end = offs[n];
    int deg = end - start;
    if (deg <= 1 || deg > 64) return;         // wave-uniform
    int ke = 0x7fffffff, vs = 0;
    if (lane < deg) { int2 t = eid2[start + lane]; ke = t.x; vs = t.y; }
#pragma unroll
    for (int k = 2; k <= 64; k <<= 1) {
        for (int j = k >> 1; j > 0; j >>= 1) {
            int partner = lane ^ j;
            int ke2 = __shfl(ke, partner, 64);
            int vs2 = __shfl(vs, partner, 64);
            bool up = ((lane & k) == 0);
            bool takemin = ((lane < partner) == up);
            bool sw = takemin ? (ke2 < ke) : (ke2 > ke);
            if (sw) { ke = ke2; vs = vs2; }
        }
    }
    if (lane < deg) eid2[start + lane] = make_int2(ke, vs);
}

// Permute edge_attr into CSR slot order (once; conv-invariant) so all 3
// agg passes read it SEQUENTIALLY instead of 256B-random. Also extract
// the compact src array so agg never touches eid2 again.
// 16 threads per slot, float4 each.
__global__ __launch_bounds__(256) void permute_kernel(
    const float* __restrict__ ea, const int2* __restrict__ eid2,
    float* __restrict__ eap, int* __restrict__ srcs)
{
    int t = blockIdx.x * 256 + threadIdx.x;
    int slot = t >> 4, c = t & 15;
    if (slot >= N_EDGES) return;
    int2 p = eid2[slot];                       // (edge id, src) — same line, 16 lanes
    float4 v = ((const float4*)(ea + (size_t)p.x * HID))[c];
    ((float4*)(eap + (size_t)slot * HID))[c] = v;
    if (c == 0) srcs[slot] = p.y;
}

// Wave-per-node aggregation: lane c = channel c. No atomics.
// agg[n][c] = sum over slots of relu(x[srcs[slot]][c] + eap[slot][c])
// eap reads are sequential (permuted); x reads hit L3 (25.6 MB resident).
// 2-edge software pipeline on the src indices.
__global__ __launch_bounds__(256) void agg_kernel(
    const float* __restrict__ x, const float* __restrict__ eap,
    const int* __restrict__ srcs, const int* __restrict__ offs,
    float* __restrict__ agg)
{
    int gt = blockIdx.x * 256 + threadIdx.x;
    int n = gt >> 6;
    int c = threadIdx.x & 63;
    if (n >= N_NODES) return;
    int nu = __builtin_amdgcn_readfirstlane(n);   // force SGPR edge-list walk
    int start = (nu == 0) ? 0 : offs[nu - 1];
    int end = offs[nu];
    float acc0 = 0.f, acc1 = 0.f;
    int i = start;
    int s0 = 0, s1 = 0;
    if (i < end) s0 = srcs[i];
    if (i + 1 < end) s1 = srcs[i + 1];
    while (i + 2 <= end) {
        int a = s0, b = s1;
        if (i + 2 < end) s0 = srcs[i + 2];        // prefetch pair
        if (i + 3 < end) s1 = srcs[i + 3];
        float xa = x[(size_t)a * HID + c];
        float pa = eap[(size_t)i * HID + c];
        float xb = x[(size_t)b * HID + c];
        float pb = eap[(size_t)(i + 1) * HID + c];
        acc0 += fmaxf(xa + pa, 0.f);
        acc1 += fmaxf(xb + pb, 0.f);
        i += 2;
    }
    if (i < end) {                                // odd remainder
        float m = x[(size_t)s0 * HID + c] + eap[(size_t)i * HID + c];
        acc0 += fmaxf(m, 0.f);
    }
    agg[(size_t)n * HID + c] = acc0 + acc1;
}

// Per-node MLP, outer-product form, weights staged in LDS, in-place on x.
// REGISTER FIX: round-2 counters showed VGPR_Count=84 with float in[64]/o[64]
// — the compiler put both arrays in SCRATCH (128 KB/block working set →
// L2 thrash, ~32 KB o[] RMW traffic per thread). Replaced with 32 NAMED
// float4 variables (macro-generated) so promotion to VGPRs is guaranteed.
// Accumulation grouping/order is bit-identical to the array version.
// o = (relu?)(W2 @ relu(W1 @ (agg+x) + b1) + b2) + x
#define REP16(M) M(0) M(1) M(2) M(3) M(4) M(5) M(6) M(7) \
                 M(8) M(9) M(10) M(11) M(12) M(13) M(14) M(15)

__global__ __launch_bounds__(256, 2) void mlp_kernel(
    const float* __restrict__ agg,
    const float* __restrict__ W1, const float* __restrict__ b1,
    const float* __restrict__ W2, const float* __restrict__ b2,
    float* __restrict__ x, int last_relu)
{
    __shared__ float sW1[HID * HID];
    __shared__ float sW2T[HID * HID];
    __shared__ float sb1[HID];
    int tid = threadIdx.x;
    for (int idx = tid; idx < HID * HID; idx += 256) {
        sW1[idx] = W1[idx];
        int r = idx >> 6, col = idx & 63;
        sW2T[col * HID + r] = W2[idx];   // transpose so layer-2 reads rows
    }
    if (tid < HID) sb1[tid] = b1[tid];
    __syncthreads();

    int n = blockIdx.x * 256 + tid;
    if (n >= N_NODES) return;

    const float4* ap = (const float4*)(agg + (size_t)n * HID);
    const float4* xp = (const float4*)(x + (size_t)n * HID);
    const float4* b2p = (const float4*)b2;

    // in_k = agg[n] + x[n]  (registers, named)
#define DECL_IN(k) float4 in##k; { float4 a = ap[k], b = xp[k]; \
    in##k.x = a.x + b.x; in##k.y = a.y + b.y; \
    in##k.z = a.z + b.z; in##k.w = a.w + b.w; }
    REP16(DECL_IN)
#undef DECL_IN

    // o_k = b2  (registers, named)
#define DECL_O(k) float4 o##k = b2p[k];
    REP16(DECL_O)
#undef DECL_O

    for (int j = 0; j < HID; ++j) {
        const float4* w1p = (const float4*)(sW1 + j * HID);
        float a0 = 0.f, a1 = 0.f, a2 = 0.f, a3 = 0.f;  // break dep chain 4-way
#define DOT4(k, acc) { float4 w = w1p[k]; \
    acc += in##k.x * w.x + in##k.y * w.y + in##k.z * w.z + in##k.w * w.w; }
        DOT4(0, a0)  DOT4(1, a1)  DOT4(2, a2)  DOT4(3, a3)
        DOT4(4, a0)  DOT4(5, a1)  DOT4(6, a2)  DOT4(7, a3)
        DOT4(8, a0)  DOT4(9, a1)  DOT4(10, a2) DOT4(11, a3)
        DOT4(12, a0) DOT4(13, a1) DOT4(14, a2) DOT4(15, a3)
#undef DOT4
        float h = fmaxf((a0 + a1) + (a2 + a3) + sb1[j], 0.f);
        const float4* w2p = (const float4*)(sW2T + j * HID);
#define AXPY(k) { float4 w = w2p[k]; \
    o##k.x += h * w.x; o##k.y += h * w.y; \
    o##k.z += h * w.z; o##k.w += h * w.w; }
        REP16(AXPY)
#undef AXPY
    }

    float4* orow = (float4*)(x + (size_t)n * HID);   // in-place: row-private
#define STORE(k) { float4 xv = xp[k]; float4 r; \
    r.x = (last_relu ? fmaxf(o##k.x, 0.f) : o##k.x) + xv.x; \
    r.y = (last_relu ? fmaxf(o##k.y, 0.f) : o##k.y) + xv.y; \
    r.z = (last_relu ? fmaxf(o##k.z, 0.f) : o##k.z) + xv.z; \
    r.w = (last_relu ? fmaxf(o##k.w, 0.f) : o##k.w) + xv.w; \
    orow[k] = r; }
    REP16(STORE)
#undef STORE
}

extern "C" void kernel_launch(void* const* d_in, const int* in_sizes, int n_in,
                              void* d_out, int out_size, void* d_ws, size_t ws_size,
                              hipStream_t stream) {
    const float* node_emb = (const float*)d_in[0];
    const float* W1 = (const float*)d_in[1];
    const float* b1 = (const float*)d_in[2];
    const float* W2 = (const float*)d_in[3];
    const float* b2 = (const float*)d_in[4];
    const float* ea = (const float*)d_in[5];
    const int* z = (const int*)d_in[6];
    const int* ei = (const int*)d_in[7];
    const int* src = ei;            // edge_index[0] = message sender
    const int* dst = ei + N_EDGES;  // edge_index[1] = aggregation target

    float* x = (float*)d_out;                       // node features live here
    // workspace layout (~294 MB of the 1 GB ws):
    float* eap = (float*)d_ws;                               // 256 MB (slot-ordered edge_attr)
    float* agg = eap + (size_t)N_EDGES * HID;                // 25.6 MB
    int2* eid2 = (int2*)(agg + (size_t)N_NODES * HID);       // 8 MB
    int* offs = (int*)(eid2 + N_EDGES);                      // 0.4 MB
    int* bsum = offs + N_NODES;                              // 98 ints (pad 128)
    int* srcs = bsum + 128;                                  // 4 MB

    const int eb = (N_EDGES + 255) / 256;            // 3907
    const int gather_blocks = (N_NODES * 16) / 256;  // 6250
    const int nodewave_blocks = (N_NODES * 64) / 256; // 25000
    const int perm_blocks = (N_EDGES * 16) / 256;    // 62500
    const int mlp_blocks = (N_NODES + 255) / 256;    // 391

    // ---- CSR build (once, reused by all 3 convs) ----
    hipMemsetAsync(offs, 0, N_NODES * sizeof(int), stream);
    gather_kernel<<<gather_blocks, 256, 0, stream>>>(node_emb, z, x);
    hist_kernel<<<eb, 256, 0, stream>>>(dst, offs);
    scan1_kernel<<<SCAN_NB, SCAN_B, 0, stream>>>(offs, bsum);
    scan2_kernel<<<1, 128, 0, stream>>>(bsum);
    scan3_kernel<<<SCAN_NB, SCAN_B, 0, stream>>>(offs, bsum);
    fill_kernel<<<eb, 256, 0, stream>>>(src, dst, offs, eid2);
    sort_kernel<<<nodewave_blocks, 256, 0, stream>>>(offs, eid2);
    permute_kernel<<<perm_blocks, 256, 0, stream>>>(ea, eid2, eap, srcs);

    // ---- 3 convs, x updated in place in d_out ----
    for (int conv = 0; conv < 3; ++conv) {
        agg_kernel<<<nodewave_blocks, 256, 0, stream>>>(x, eap, srcs, offs, agg);
        mlp_kernel<<<mlp_blocks, 256, 0, stream>>>(
            agg, W1 + conv * HID * HID, b1 + conv * HID,
            W2 + conv * HID * HID, b2 + conv * HID,
            x, conv < 2 ? 1 : 0);
    }
}

// Round 6
// 991.952 us; speedup vs baseline: 1.2849x; 1.0749x over previous
//
#include <hip/hip_runtime.h>

#define N_NODES 100000
#define N_EDGES 1000000
#define HID 64
#define SCAN_B 1024
#define SCAN_NB ((N_NODES + SCAN_B - 1) / SCAN_B)   // 98

// x[n] = node_emb[z[n]]  (16 threads per node, float4 each)
__global__ __launch_bounds__(256) void gather_kernel(
    const float* __restrict__ node_emb, const int* __restrict__ z,
    float* __restrict__ x)
{
    int t = blockIdx.x * 256 + threadIdx.x;
    int n = t >> 4, c = t & 15;
    if (n >= N_NODES) return;
    int zi = z[n];
    float4 v = ((const float4*)(node_emb + (size_t)zi * HID))[c];
    ((float4*)(x + (size_t)n * HID))[c] = v;
}

// offs[dst[e]] += 1  (degree histogram; offs pre-zeroed)
__global__ __launch_bounds__(256) void hist_kernel(
    const int* __restrict__ dst, int* __restrict__ offs)
{
    int e = blockIdx.x * 256 + threadIdx.x;
    if (e < N_EDGES) atomicAdd(&offs[dst[e]], 1);
}

// ---- multi-block exclusive scan (3 phases) ----
// Phase 1: per-block exclusive scan in place, block totals to bsum.
__global__ __launch_bounds__(1024) void scan1_kernel(
    int* __restrict__ offs, int* __restrict__ bsum)
{
    __shared__ int wsum[16];
    int tid = threadIdx.x, lane = tid & 63, wid = tid >> 6;
    int i = blockIdx.x * SCAN_B + tid;
    int v = (i < N_NODES) ? offs[i] : 0;
    int s = v;
#pragma unroll
    for (int d = 1; d < 64; d <<= 1) {
        int t = __shfl_up(s, (unsigned)d, 64);
        if (lane >= d) s += t;
    }
    if (lane == 63) wsum[wid] = s;
    __syncthreads();
    if (wid == 0) {
        int w = (lane < 16) ? wsum[lane] : 0;
#pragma unroll
        for (int d = 1; d < 16; d <<= 1) {
            int t = __shfl_up(w, (unsigned)d, 64);
            if (lane >= d) w += t;
        }
        if (lane < 16) wsum[lane] = w;
    }
    __syncthreads();
    int woff = (wid == 0) ? 0 : wsum[wid - 1];
    if (i < N_NODES) offs[i] = woff + s - v;     // block-local exclusive
    if (tid == 1023) bsum[blockIdx.x] = wsum[15]; // block total
}

// Phase 2: exclusive scan of the 98 block totals (1 block, 2 waves).
__global__ __launch_bounds__(128) void scan2_kernel(int* __restrict__ bsum)
{
    __shared__ int ws[2];
    int tid = threadIdx.x, lane = tid & 63, wid = tid >> 6;
    int v = (tid < SCAN_NB) ? bsum[tid] : 0;
    int s = v;
#pragma unroll
    for (int d = 1; d < 64; d <<= 1) {
        int t = __shfl_up(s, (unsigned)d, 64);
        if (lane >= d) s += t;
    }
    if (lane == 63) ws[wid] = s;
    __syncthreads();
    int add = (wid == 1) ? ws[0] : 0;
    if (tid < SCAN_NB) bsum[tid] = add + s - v;  // exclusive
}

// Phase 3: add block offset. Published with atomicExch so the downstream
// atomicAdd cursor RMW (fill_kernel, possibly other XCD) never RMWs a
// stale value: atomic->atomic stays at the coherent point.
__global__ __launch_bounds__(1024) void scan3_kernel(
    int* __restrict__ offs, const int* __restrict__ bsum)
{
    int i = blockIdx.x * SCAN_B + threadIdx.x;
    if (i < N_NODES) {
        int v = offs[i] + bsum[blockIdx.x];
        atomicExch(&offs[i], v);
    }
}

// eid2[slot] = (e, src[e]); offs becomes END offsets after this
// (start[n] = offs[n-1] afterwards, start[0] = 0).
__global__ __launch_bounds__(256) void fill_kernel(
    const int* __restrict__ src, const int* __restrict__ dst,
    int* __restrict__ offs, int2* __restrict__ eid2)
{
    int e = blockIdx.x * 256 + threadIdx.x;
    if (e < N_EDGES) {
        int d = dst[e];
        int pos = atomicAdd(&offs[d], 1);
        eid2[pos] = make_int2(e, src[e]);
    }
}

// Canonicalize each node's slot range to ascending edge-id order so the
// aggregation sum order is launch-invariant (fill's atomic cursor order is
// not). Wave per node, 64-lane bitonic sort, INT_MAX padding. Degrees are
// ~Poisson(10); P(deg>64) ~ 1e-40 — such nodes are left in cursor order.
__global__ __launch_bounds__(256) void sort_kernel(
    const int* __restrict__ offs, int2* __restrict__ eid2)
{
    int gt = blockIdx.x * 256 + threadIdx.x;
    int n = gt >> 6;
    int lane = threadIdx.x & 63;
    if (n >= N_NODES) return;                 // wave-uniform
    int start = (n == 0) ? 0 : offs[n - 1];
    int end = offs[n];
    int deg = end - start;
    if (deg <= 1 || deg > 64) return;         // wave-uniform
    int ke = 0x7fffffff, vs = 0;
    if (lane < deg) { int2 t = eid2[start + lane]; ke = t.x; vs = t.y; }
#pragma unroll
    for (int k = 2; k <= 64; k <<= 1) {
        for (int j = k >> 1; j > 0; j >>= 1) {
            int partner = lane ^ j;
            int ke2 = __shfl(ke, partner, 64);
            int vs2 = __shfl(vs, partner, 64);
            bool up = ((lane & k) == 0);
            bool takemin = ((lane < partner) == up);
            bool sw = takemin ? (ke2 < ke) : (ke2 > ke);
            if (sw) { ke = ke2; vs = vs2; }
        }
    }
    if (lane < deg) eid2[start + lane] = make_int2(ke, vs);
}

// Wave-per-node aggregation, 4 edges in flight:
//   lane = g*16 + c4  (g = edge sub-index 0..3, c4 = float4 channel block)
// Each 16-lane group handles one edge's full 64-channel row as float4
// (16 B/lane coalescing sweet spot); 4 consecutive slots per iteration.
// FIRST conv additionally permutes ea into CSR slot order (eap) and
// extracts srcs — fusing the old permute_kernel's work into the read
// it already had to do. Convs 2,3 stream eap sequentially.
// Cross-group reduce via 2 shfl_xor steps; lanes 0-15 write the row.
template<int FIRST>
__global__ __launch_bounds__(256) void agg_kernel(
    const float* __restrict__ x, const float* __restrict__ ea,
    float* __restrict__ eap, const int2* __restrict__ eid2,
    int* __restrict__ srcs, const int* __restrict__ offs,
    float* __restrict__ agg)
{
    int gt = blockIdx.x * 256 + threadIdx.x;
    int n = gt >> 6;
    if (n >= N_NODES) return;
    int lane = threadIdx.x & 63;
    int g = lane >> 4, c4 = lane & 15;
    int nu = __builtin_amdgcn_readfirstlane(n);   // SGPR edge-list walk
    int start = (nu == 0) ? 0 : offs[nu - 1];
    int end = offs[nu];
    float4 acc = make_float4(0.f, 0.f, 0.f, 0.f);
    for (int i = start + g; i < end; i += 4) {
        int sidx;
        float4 e4;
        if (FIRST) {
            int2 p = eid2[i];                     // broadcast within group
            sidx = p.y;
            if (c4 == 0) srcs[i] = sidx;
            e4 = ((const float4*)(ea + (size_t)p.x * HID))[c4];
            ((float4*)(eap + (size_t)i * HID))[c4] = e4;
        } else {
            sidx = srcs[i];                       // broadcast within group
            e4 = ((const float4*)(eap + (size_t)i * HID))[c4];  // sequential
        }
        float4 x4 = ((const float4*)(x + (size_t)sidx * HID))[c4];
        acc.x += fmaxf(x4.x + e4.x, 0.f);
        acc.y += fmaxf(x4.y + e4.y, 0.f);
        acc.z += fmaxf(x4.z + e4.z, 0.f);
        acc.w += fmaxf(x4.w + e4.w, 0.f);
    }
    // reduce over the 4 edge groups: (g0+g1)+(g2+g3) per channel
    acc.x += __shfl_xor(acc.x, 16, 64);
    acc.y += __shfl_xor(acc.y, 16, 64);
    acc.z += __shfl_xor(acc.z, 16, 64);
    acc.w += __shfl_xor(acc.w, 16, 64);
    acc.x += __shfl_xor(acc.x, 32, 64);
    acc.y += __shfl_xor(acc.y, 32, 64);
    acc.z += __shfl_xor(acc.z, 32, 64);
    acc.w += __shfl_xor(acc.w, 32, 64);
    if (g == 0) ((float4*)(agg + (size_t)n * HID))[c4] = acc;
}

// Per-node MLP, outer-product form, weights staged in LDS, in-place on x.
// in/o live in 32 NAMED float4 registers (macro-generated) — guaranteed
// VGPR promotion. o = (relu?)(W2 @ relu(W1 @ (agg+x) + b1) + b2) + x
#define REP16(M) M(0) M(1) M(2) M(3) M(4) M(5) M(6) M(7) \
                 M(8) M(9) M(10) M(11) M(12) M(13) M(14) M(15)

__global__ __launch_bounds__(256, 2) void mlp_kernel(
    const float* __restrict__ agg,
    const float* __restrict__ W1, const float* __restrict__ b1,
    const float* __restrict__ W2, const float* __restrict__ b2,
    float* __restrict__ x, int last_relu)
{
    __shared__ float sW1[HID * HID];
    __shared__ float sW2T[HID * HID];
    __shared__ float sb1[HID];
    int tid = threadIdx.x;
    for (int idx = tid; idx < HID * HID; idx += 256) {
        sW1[idx] = W1[idx];
        int r = idx >> 6, col = idx & 63;
        sW2T[col * HID + r] = W2[idx];   // transpose so layer-2 reads rows
    }
    if (tid < HID) sb1[tid] = b1[tid];
    __syncthreads();

    int n = blockIdx.x * 256 + tid;
    if (n >= N_NODES) return;

    const float4* ap = (const float4*)(agg + (size_t)n * HID);
    const float4* xp = (const float4*)(x + (size_t)n * HID);
    const float4* b2p = (const float4*)b2;

    // in_k = agg[n] + x[n]  (registers, named)
#define DECL_IN(k) float4 in##k; { float4 a = ap[k], b = xp[k]; \
    in##k.x = a.x + b.x; in##k.y = a.y + b.y; \
    in##k.z = a.z + b.z; in##k.w = a.w + b.w; }
    REP16(DECL_IN)
#undef DECL_IN

    // o_k = b2  (registers, named)
#define DECL_O(k) float4 o##k = b2p[k];
    REP16(DECL_O)
#undef DECL_O

    for (int j = 0; j < HID; ++j) {
        const float4* w1p = (const float4*)(sW1 + j * HID);
        float a0 = 0.f, a1 = 0.f, a2 = 0.f, a3 = 0.f;  // break dep chain 4-way
#define DOT4(k, acc) { float4 w = w1p[k]; \
    acc += in##k.x * w.x + in##k.y * w.y + in##k.z * w.z + in##k.w * w.w; }
        DOT4(0, a0)  DOT4(1, a1)  DOT4(2, a2)  DOT4(3, a3)
        DOT4(4, a0)  DOT4(5, a1)  DOT4(6, a2)  DOT4(7, a3)
        DOT4(8, a0)  DOT4(9, a1)  DOT4(10, a2) DOT4(11, a3)
        DOT4(12, a0) DOT4(13, a1) DOT4(14, a2) DOT4(15, a3)
#undef DOT4
        float h = fmaxf((a0 + a1) + (a2 + a3) + sb1[j], 0.f);
        const float4* w2p = (const float4*)(sW2T + j * HID);
#define AXPY(k) { float4 w = w2p[k]; \
    o##k.x += h * w.x; o##k.y += h * w.y; \
    o##k.z += h * w.z; o##k.w += h * w.w; }
        REP16(AXPY)
#undef AXPY
    }

    float4* orow = (float4*)(x + (size_t)n * HID);   // in-place: row-private
#define STORE(k) { float4 xv = xp[k]; float4 r; \
    r.x = (last_relu ? fmaxf(o##k.x, 0.f) : o##k.x) + xv.x; \
    r.y = (last_relu ? fmaxf(o##k.y, 0.f) : o##k.y) + xv.y; \
    r.z = (last_relu ? fmaxf(o##k.z, 0.f) : o##k.z) + xv.z; \
    r.w = (last_relu ? fmaxf(o##k.w, 0.f) : o##k.w) + xv.w; \
    orow[k] = r; }
    REP16(STORE)
#undef STORE
}

extern "C" void kernel_launch(void* const* d_in, const int* in_sizes, int n_in,
                              void* d_out, int out_size, void* d_ws, size_t ws_size,
                              hipStream_t stream) {
    const float* node_emb = (const float*)d_in[0];
    const float* W1 = (const float*)d_in[1];
    const float* b1 = (const float*)d_in[2];
    const float* W2 = (const float*)d_in[3];
    const float* b2 = (const float*)d_in[4];
    const float* ea = (const float*)d_in[5];
    const int* z = (const int*)d_in[6];
    const int* ei = (const int*)d_in[7];
    const int* src = ei;            // edge_index[0] = message sender
    const int* dst = ei + N_EDGES;  // edge_index[1] = aggregation target

    float* x = (float*)d_out;                       // node features live here
    // workspace layout (~294 MB of the 1 GB ws):
    float* eap = (float*)d_ws;                               // 256 MB (slot-ordered edge_attr)
    float* agg = eap + (size_t)N_EDGES * HID;                // 25.6 MB
    int2* eid2 = (int2*)(agg + (size_t)N_NODES * HID);       // 8 MB
    int* offs = (int*)(eid2 + N_EDGES);                      // 0.4 MB
    int* bsum = offs + N_NODES;                              // 98 ints (pad 128)
    int* srcs = bsum + 128;                                  // 4 MB

    const int eb = (N_EDGES + 255) / 256;            // 3907
    const int gather_blocks = (N_NODES * 16) / 256;  // 6250
    const int nodewave_blocks = (N_NODES * 64) / 256; // 25000
    const int mlp_blocks = (N_NODES + 255) / 256;    // 391

    // ---- CSR build (once, reused by all 3 convs) ----
    hipMemsetAsync(offs, 0, N_NODES * sizeof(int), stream);
    gather_kernel<<<gather_blocks, 256, 0, stream>>>(node_emb, z, x);
    hist_kernel<<<eb, 256, 0, stream>>>(dst, offs);
    scan1_kernel<<<SCAN_NB, SCAN_B, 0, stream>>>(offs, bsum);
    scan2_kernel<<<1, 128, 0, stream>>>(bsum);
    scan3_kernel<<<SCAN_NB, SCAN_B, 0, stream>>>(offs, bsum);
    fill_kernel<<<eb, 256, 0, stream>>>(src, dst, offs, eid2);
    sort_kernel<<<nodewave_blocks, 256, 0, stream>>>(offs, eid2);

    // ---- 3 convs, x updated in place in d_out ----
    // conv 0: agg fuses the ea->eap permute + srcs extraction
    agg_kernel<1><<<nodewave_blocks, 256, 0, stream>>>(x, ea, eap, eid2, srcs, offs, agg);
    mlp_kernel<<<mlp_blocks, 256, 0, stream>>>(
        agg, W1, b1, W2, b2, x, 1);
    for (int conv = 1; conv < 3; ++conv) {
        agg_kernel<0><<<nodewave_blocks, 256, 0, stream>>>(x, ea, eap, eid2, srcs, offs, agg);
        mlp_kernel<<<mlp_blocks, 256, 0, stream>>>(
            agg, W1 + conv * HID * HID, b1 + conv * HID,
            W2 + conv * HID * HID, b2 + conv * HID,
            x, conv < 2 ? 1 : 0);
    }
}

// Round 8
// 942.615 us; speedup vs baseline: 1.3521x; 1.0523x over previous
//
#include <hip/hip_runtime.h>

#define N_NODES 100000
#define N_EDGES 1000000
#define HID 64
#define SCAN_B 1024
#define SCAN_NB ((N_NODES + SCAN_B - 1) / SCAN_B)   // 98
#define GATHER_BLOCKS ((N_NODES * 16) / 256)        // 6250
#define HIST_BLOCKS ((N_EDGES + 255) / 256)         // 3907

// Fused: x[n] = node_emb[z[n]] (16 thr/node, float4)  +  degree histogram.
// Independent work, one dispatch (branch on blockIdx is wave-uniform).
__global__ __launch_bounds__(256) void prep_kernel(
    const float* __restrict__ node_emb, const int* __restrict__ z,
    float* __restrict__ x, const int* __restrict__ dst, int* __restrict__ offs)
{
    if (blockIdx.x < GATHER_BLOCKS) {
        int t = blockIdx.x * 256 + threadIdx.x;
        int n = t >> 4, c = t & 15;
        if (n >= N_NODES) return;
        int zi = z[n];
        float4 v = ((const float4*)(node_emb + (size_t)zi * HID))[c];
        ((float4*)(x + (size_t)n * HID))[c] = v;
    } else {
        int e = (blockIdx.x - GATHER_BLOCKS) * 256 + threadIdx.x;
        if (e < N_EDGES) atomicAdd(&offs[dst[e]], 1);
    }
}

// ---- multi-block exclusive scan (3 phases) ----
// Phase 1: per-block exclusive scan in place, block totals to bsum.
__global__ __launch_bounds__(1024) void scan1_kernel(
    int* __restrict__ offs, int* __restrict__ bsum)
{
    __shared__ int wsum[16];
    int tid = threadIdx.x, lane = tid & 63, wid = tid >> 6;
    int i = blockIdx.x * SCAN_B + tid;
    int v = (i < N_NODES) ? offs[i] : 0;
    int s = v;
#pragma unroll
    for (int d = 1; d < 64; d <<= 1) {
        int t = __shfl_up(s, (unsigned)d, 64);
        if (lane >= d) s += t;
    }
    if (lane == 63) wsum[wid] = s;
    __syncthreads();
    if (wid == 0) {
        int w = (lane < 16) ? wsum[lane] : 0;
#pragma unroll
        for (int d = 1; d < 16; d <<= 1) {
            int t = __shfl_up(w, (unsigned)d, 64);
            if (lane >= d) w += t;
        }
        if (lane < 16) wsum[lane] = w;
    }
    __syncthreads();
    int woff = (wid == 0) ? 0 : wsum[wid - 1];
    if (i < N_NODES) offs[i] = woff + s - v;     // block-local exclusive
    if (tid == 1023) bsum[blockIdx.x] = wsum[15]; // block total
}

// Phase 2: exclusive scan of the 98 block totals (1 block, 2 waves).
__global__ __launch_bounds__(128) void scan2_kernel(int* __restrict__ bsum)
{
    __shared__ int ws[2];
    int tid = threadIdx.x, lane = tid & 63, wid = tid >> 6;
    int v = (tid < SCAN_NB) ? bsum[tid] : 0;
    int s = v;
#pragma unroll
    for (int d = 1; d < 64; d <<= 1) {
        int t = __shfl_up(s, (unsigned)d, 64);
        if (lane >= d) s += t;
    }
    if (lane == 63) ws[wid] = s;
    __syncthreads();
    int add = (wid == 1) ? ws[0] : 0;
    if (tid < SCAN_NB) bsum[tid] = add + s - v;  // exclusive
}

// Phase 3: add block offset. Published with atomicExch so the downstream
// atomicAdd cursor RMW (fill_kernel, possibly other XCD) never RMWs a
// stale value: atomic->atomic stays at the coherent point.
__global__ __launch_bounds__(1024) void scan3_kernel(
    int* __restrict__ offs, const int* __restrict__ bsum)
{
    int i = blockIdx.x * SCAN_B + threadIdx.x;
    if (i < N_NODES) {
        int v = offs[i] + bsum[blockIdx.x];
        atomicExch(&offs[i], v);
    }
}

// eid2[slot] = (e, src[e]); offs becomes END offsets after this
// (start[n] = offs[n-1] afterwards, start[0] = 0).
__global__ __launch_bounds__(256) void fill_kernel(
    const int* __restrict__ src, const int* __restrict__ dst,
    int* __restrict__ offs, int2* __restrict__ eid2)
{
    int e = blockIdx.x * 256 + threadIdx.x;
    if (e < N_EDGES) {
        int d = dst[e];
        int pos = atomicAdd(&offs[d], 1);
        eid2[pos] = make_int2(e, src[e]);
    }
}

// Canonicalize each node's slot range to ascending edge-id order so the
// aggregation sum order is launch-invariant (fill's atomic cursor order is
// not). Wave per node, 64-lane bitonic sort, INT_MAX padding. Degrees are
// ~Poisson(10); P(deg>64) ~ 1e-40 — such nodes are left in cursor order.
// (Safe shuffles: trip counts are lane-uniform here.)
__global__ __launch_bounds__(256) void sort_kernel(
    const int* __restrict__ offs, int2* __restrict__ eid2)
{
    int gt = blockIdx.x * 256 + threadIdx.x;
    int n = gt >> 6;
    int lane = threadIdx.x & 63;
    if (n >= N_NODES) return;                 // wave-uniform
    int start = (n == 0) ? 0 : offs[n - 1];
    int end = offs[n];
    int deg = end - start;
    if (deg <= 1 || deg > 64) return;         // wave-uniform
    int ke = 0x7fffffff, vs = 0;
    if (lane < deg) { int2 t = eid2[start + lane]; ke = t.x; vs = t.y; }
#pragma unroll
    for (int k = 2; k <= 64; k <<= 1) {
        for (int j = k >> 1; j > 0; j >>= 1) {
            int partner = lane ^ j;
            int ke2 = __shfl(ke, partner, 64);
            int vs2 = __shfl(vs, partner, 64);
            bool up = ((lane & k) == 0);
            bool takemin = ((lane < partner) == up);
            bool sw = takemin ? (ke2 < ke) : (ke2 > ke);
            if (sw) { ke = ke2; vs = vs2; }
        }
    }
    if (lane < deg) eid2[start + lane] = make_int2(ke, vs);
}

// Wave-per-node aggregation, 4 edges in flight:
//   lane = g*16 + c4  (g = edge sub-index 0..3, c4 = float4 channel block)
// The node's WHOLE edge list is hoisted into registers (lane l holds
// eid2[start+l]), so loop addresses come from register shuffles.
// BUGFIX (round 7): ds_bpermute reads UNDEFINED data from lanes inactive
// under the current exec mask. The old per-group trip count (k<dmax step 4)
// let an active group shuffle-read a lane in an already-exited group
// (e.g. deg=17, j=4: g0 reads lane 16 while group 1 is inactive).
// Fix: UNIFORM iteration count (iters from SGPR dmax) — every lane
// executes every __shfl; only the load+accumulate is predicated.
__global__ __launch_bounds__(256) void agg_kernel(
    const float* __restrict__ x, const float* __restrict__ ea,
    const int2* __restrict__ eid2, const int* __restrict__ offs,
    float* __restrict__ agg)
{
    int gt = blockIdx.x * 256 + threadIdx.x;
    int n = gt >> 6;
    if (n >= N_NODES) return;
    int lane = threadIdx.x & 63;
    int g = lane >> 4, c4 = lane & 15;
    int nu = __builtin_amdgcn_readfirstlane(n);   // SGPR edge-list walk
    int start = (nu == 0) ? 0 : offs[nu - 1];
    int end = offs[nu];
    int deg = end - start;
    int2 my = make_int2(0, 0);
    if (lane < deg) my = eid2[start + lane];      // one load, whole edge list
    float4 acc = make_float4(0.f, 0.f, 0.f, 0.f);
    int dmax = deg < 64 ? deg : 64;
    int iters = (dmax + 3) >> 2;                  // wave-uniform trip count
    for (int j = 0; j < iters; ++j) {
        int k = g + 4 * j;
        int eidx = __shfl(my.x, k, 64);           // all 64 lanes active here
        int sidx = __shfl(my.y, k, 64);
        if (k < dmax) {                           // predicate work only
            float4 e4 = ((const float4*)(ea + (size_t)eidx * HID))[c4];
            float4 x4 = ((const float4*)(x + (size_t)sidx * HID))[c4];
            acc.x += fmaxf(x4.x + e4.x, 0.f);
            acc.y += fmaxf(x4.y + e4.y, 0.f);
            acc.z += fmaxf(x4.z + e4.z, 0.f);
            acc.w += fmaxf(x4.w + e4.w, 0.f);
        }
    }
    for (int i = start + 64 + g; i < end; i += 4) {   // deg>64: never in practice
        int2 p = eid2[i];
        float4 e4 = ((const float4*)(ea + (size_t)p.x * HID))[c4];
        float4 x4 = ((const float4*)(x + (size_t)p.y * HID))[c4];
        acc.x += fmaxf(x4.x + e4.x, 0.f);
        acc.y += fmaxf(x4.y + e4.y, 0.f);
        acc.z += fmaxf(x4.z + e4.z, 0.f);
        acc.w += fmaxf(x4.w + e4.w, 0.f);
    }
    // reduce over the 4 edge groups: (g0+g1)+(g2+g3) per channel
    acc.x += __shfl_xor(acc.x, 16, 64);
    acc.y += __shfl_xor(acc.y, 16, 64);
    acc.z += __shfl_xor(acc.z, 16, 64);
    acc.w += __shfl_xor(acc.w, 16, 64);
    acc.x += __shfl_xor(acc.x, 32, 64);
    acc.y += __shfl_xor(acc.y, 32, 64);
    acc.z += __shfl_xor(acc.z, 32, 64);
    acc.w += __shfl_xor(acc.w, 32, 64);
    if (g == 0) ((float4*)(agg + (size_t)n * HID))[c4] = acc;
}

// Per-node MLP, outer-product form, weights staged in LDS, in-place on x.
// in/o live in 32 NAMED float4 registers (macro-generated) — guaranteed
// VGPR promotion. o = (relu?)(W2 @ relu(W1 @ (agg+x) + b1) + b2) + x
#define REP16(M) M(0) M(1) M(2) M(3) M(4) M(5) M(6) M(7) \
                 M(8) M(9) M(10) M(11) M(12) M(13) M(14) M(15)

__global__ __launch_bounds__(256, 2) void mlp_kernel(
    const float* __restrict__ agg,
    const float* __restrict__ W1, const float* __restrict__ b1,
    const float* __restrict__ W2, const float* __restrict__ b2,
    float* __restrict__ x, int last_relu)
{
    __shared__ float sW1[HID * HID];
    __shared__ float sW2T[HID * HID];
    __shared__ float sb1[HID];
    int tid = threadIdx.x;
    for (int idx = tid; idx < HID * HID; idx += 256) {
        sW1[idx] = W1[idx];
        int r = idx >> 6, col = idx & 63;
        sW2T[col * HID + r] = W2[idx];   // transpose so layer-2 reads rows
    }
    if (tid < HID) sb1[tid] = b1[tid];
    __syncthreads();

    int n = blockIdx.x * 256 + tid;
    if (n >= N_NODES) return;

    const float4* ap = (const float4*)(agg + (size_t)n * HID);
    const float4* xp = (const float4*)(x + (size_t)n * HID);
    const float4* b2p = (const float4*)b2;

    // in_k = agg[n] + x[n]  (registers, named)
#define DECL_IN(k) float4 in##k; { float4 a = ap[k], b = xp[k]; \
    in##k.x = a.x + b.x; in##k.y = a.y + b.y; \
    in##k.z = a.z + b.z; in##k.w = a.w + b.w; }
    REP16(DECL_IN)
#undef DECL_IN

    // o_k = b2  (registers, named)
#define DECL_O(k) float4 o##k = b2p[k];
    REP16(DECL_O)
#undef DECL_O

    for (int j = 0; j < HID; ++j) {
        const float4* w1p = (const float4*)(sW1 + j * HID);
        float a0 = 0.f, a1 = 0.f, a2 = 0.f, a3 = 0.f;  // break dep chain 4-way
#define DOT4(k, acc) { float4 w = w1p[k]; \
    acc += in##k.x * w.x + in##k.y * w.y + in##k.z * w.z + in##k.w * w.w; }
        DOT4(0, a0)  DOT4(1, a1)  DOT4(2, a2)  DOT4(3, a3)
        DOT4(4, a0)  DOT4(5, a1)  DOT4(6, a2)  DOT4(7, a3)
        DOT4(8, a0)  DOT4(9, a1)  DOT4(10, a2) DOT4(11, a3)
        DOT4(12, a0) DOT4(13, a1) DOT4(14, a2) DOT4(15, a3)
#undef DOT4
        float h = fmaxf((a0 + a1) + (a2 + a3) + sb1[j], 0.f);
        const float4* w2p = (const float4*)(sW2T + j * HID);
#define AXPY(k) { float4 w = w2p[k]; \
    o##k.x += h * w.x; o##k.y += h * w.y; \
    o##k.z += h * w.z; o##k.w += h * w.w; }
        REP16(AXPY)
#undef AXPY
    }

    float4* orow = (float4*)(x + (size_t)n * HID);   // in-place: row-private
#define STORE(k) { float4 xv = xp[k]; float4 r; \
    r.x = (last_relu ? fmaxf(o##k.x, 0.f) : o##k.x) + xv.x; \
    r.y = (last_relu ? fmaxf(o##k.y, 0.f) : o##k.y) + xv.y; \
    r.z = (last_relu ? fmaxf(o##k.z, 0.f) : o##k.z) + xv.z; \
    r.w = (last_relu ? fmaxf(o##k.w, 0.f) : o##k.w) + xv.w; \
    orow[k] = r; }
    REP16(STORE)
#undef STORE
}

extern "C" void kernel_launch(void* const* d_in, const int* in_sizes, int n_in,
                              void* d_out, int out_size, void* d_ws, size_t ws_size,
                              hipStream_t stream) {
    const float* node_emb = (const float*)d_in[0];
    const float* W1 = (const float*)d_in[1];
    const float* b1 = (const float*)d_in[2];
    const float* W2 = (const float*)d_in[3];
    const float* b2 = (const float*)d_in[4];
    const float* ea = (const float*)d_in[5];
    const int* z = (const int*)d_in[6];
    const int* ei = (const int*)d_in[7];
    const int* src = ei;            // edge_index[0] = message sender
    const int* dst = ei + N_EDGES;  // edge_index[1] = aggregation target

    float* x = (float*)d_out;                       // node features live here
    // workspace layout (~38 MB):
    float* agg = (float*)d_ws;                               // 25.6 MB
    int2* eid2 = (int2*)(agg + (size_t)N_NODES * HID);       // 8 MB
    int* offs = (int*)(eid2 + N_EDGES);                      // 0.4 MB
    int* bsum = offs + N_NODES;                              // 98 ints (pad 128)

    const int eb = (N_EDGES + 255) / 256;            // 3907
    const int nodewave_blocks = (N_NODES * 64) / 256; // 25000
    const int mlp_blocks = (N_NODES + 255) / 256;    // 391

    // ---- CSR build (once, reused by all 3 convs) ----
    hipMemsetAsync(offs, 0, N_NODES * sizeof(int), stream);
    prep_kernel<<<GATHER_BLOCKS + HIST_BLOCKS, 256, 0, stream>>>(
        node_emb, z, x, dst, offs);
    scan1_kernel<<<SCAN_NB, SCAN_B, 0, stream>>>(offs, bsum);
    scan2_kernel<<<1, 128, 0, stream>>>(bsum);
    scan3_kernel<<<SCAN_NB, SCAN_B, 0, stream>>>(offs, bsum);
    fill_kernel<<<eb, 256, 0, stream>>>(src, dst, offs, eid2);
    sort_kernel<<<nodewave_blocks, 256, 0, stream>>>(offs, eid2);

    // ---- 3 convs, x updated in place in d_out ----
    for (int conv = 0; conv < 3; ++conv) {
        agg_kernel<<<nodewave_blocks, 256, 0, stream>>>(x, ea, eid2, offs, agg);
        mlp_kernel<<<mlp_blocks, 256, 0, stream>>>(
            agg, W1 + conv * HID * HID, b1 + conv * HID,
            W2 + conv * HID * HID, b2 + conv * HID,
            x, conv < 2 ? 1 : 0);
    }
}

// Round 9
// 803.773 us; speedup vs baseline: 1.5857x; 1.1727x over previous
//
#include <hip/hip_runtime.h>

#define N_NODES 100000
#define N_EDGES 1000000
#define HID 64
#define SCAN_B 1024
#define SCAN_NB ((N_NODES + SCAN_B - 1) / SCAN_B)   // 98
#define GATHER_BLOCKS ((N_NODES * 16) / 256)        // 6250
#define HIST_BLOCKS ((N_EDGES + 255) / 256)         // 3907

typedef __attribute__((ext_vector_type(8))) short short8;   // 8 bf16 (4 VGPR)
typedef __attribute__((ext_vector_type(4))) float f32x4;

// f32 -> bf16 bits, round-to-nearest-even
__device__ __forceinline__ unsigned short f2bf(float f) {
    unsigned u = __float_as_uint(f);
    u += 0x7fffu + ((u >> 16) & 1u);
    return (unsigned short)(u >> 16);
}
__device__ __forceinline__ short8 pack8(float4 a, float4 b) {
    short8 r;
    r[0] = (short)f2bf(a.x); r[1] = (short)f2bf(a.y);
    r[2] = (short)f2bf(a.z); r[3] = (short)f2bf(a.w);
    r[4] = (short)f2bf(b.x); r[5] = (short)f2bf(b.y);
    r[6] = (short)f2bf(b.z); r[7] = (short)f2bf(b.w);
    return r;
}
// 8 consecutive k-elements of weight row `row` starting at k0 (f32 -> bf16)
__device__ __forceinline__ short8 ldw(const float* __restrict__ W, int row, int k0) {
    const float4* p = (const float4*)(W + (size_t)row * HID + k0);
    return pack8(p[0], p[1]);
}

// Fused: x[n] = node_emb[z[n]] (16 thr/node, float4)  +  degree histogram.
__global__ __launch_bounds__(256) void prep_kernel(
    const float* __restrict__ node_emb, const int* __restrict__ z,
    float* __restrict__ x, const int* __restrict__ dst, int* __restrict__ offs)
{
    if (blockIdx.x < GATHER_BLOCKS) {
        int t = blockIdx.x * 256 + threadIdx.x;
        int n = t >> 4, c = t & 15;
        if (n >= N_NODES) return;
        int zi = z[n];
        float4 v = ((const float4*)(node_emb + (size_t)zi * HID))[c];
        ((float4*)(x + (size_t)n * HID))[c] = v;
    } else {
        int e = (blockIdx.x - GATHER_BLOCKS) * 256 + threadIdx.x;
        if (e < N_EDGES) atomicAdd(&offs[dst[e]], 1);
    }
}

// ---- multi-block exclusive scan (3 phases) ----
__global__ __launch_bounds__(1024) void scan1_kernel(
    int* __restrict__ offs, int* __restrict__ bsum)
{
    __shared__ int wsum[16];
    int tid = threadIdx.x, lane = tid & 63, wid = tid >> 6;
    int i = blockIdx.x * SCAN_B + tid;
    int v = (i < N_NODES) ? offs[i] : 0;
    int s = v;
#pragma unroll
    for (int d = 1; d < 64; d <<= 1) {
        int t = __shfl_up(s, (unsigned)d, 64);
        if (lane >= d) s += t;
    }
    if (lane == 63) wsum[wid] = s;
    __syncthreads();
    if (wid == 0) {
        int w = (lane < 16) ? wsum[lane] : 0;
#pragma unroll
        for (int d = 1; d < 16; d <<= 1) {
            int t = __shfl_up(w, (unsigned)d, 64);
            if (lane >= d) w += t;
        }
        if (lane < 16) wsum[lane] = w;
    }
    __syncthreads();
    int woff = (wid == 0) ? 0 : wsum[wid - 1];
    if (i < N_NODES) offs[i] = woff + s - v;     // block-local exclusive
    if (tid == 1023) bsum[blockIdx.x] = wsum[15]; // block total
}

__global__ __launch_bounds__(128) void scan2_kernel(int* __restrict__ bsum)
{
    __shared__ int ws[2];
    int tid = threadIdx.x, lane = tid & 63, wid = tid >> 6;
    int v = (tid < SCAN_NB) ? bsum[tid] : 0;
    int s = v;
#pragma unroll
    for (int d = 1; d < 64; d <<= 1) {
        int t = __shfl_up(s, (unsigned)d, 64);
        if (lane >= d) s += t;
    }
    if (lane == 63) ws[wid] = s;
    __syncthreads();
    int add = (wid == 1) ? ws[0] : 0;
    if (tid < SCAN_NB) bsum[tid] = add + s - v;  // exclusive
}

__global__ __launch_bounds__(1024) void scan3_kernel(
    int* __restrict__ offs, const int* __restrict__ bsum)
{
    int i = blockIdx.x * SCAN_B + threadIdx.x;
    if (i < N_NODES) {
        int v = offs[i] + bsum[blockIdx.x];
        atomicExch(&offs[i], v);   // publish at coherent point for fill's RMW
    }
}

// eid2[slot] = (e, src[e]); offs becomes END offsets after this.
__global__ __launch_bounds__(256) void fill_kernel(
    const int* __restrict__ src, const int* __restrict__ dst,
    int* __restrict__ offs, int2* __restrict__ eid2)
{
    int e = blockIdx.x * 256 + threadIdx.x;
    if (e < N_EDGES) {
        int d = dst[e];
        int pos = atomicAdd(&offs[d], 1);
        eid2[pos] = make_int2(e, src[e]);
    }
}

// Canonicalize slot ranges to ascending edge-id order (launch-invariant sums).
__global__ __launch_bounds__(256) void sort_kernel(
    const int* __restrict__ offs, int2* __restrict__ eid2)
{
    int gt = blockIdx.x * 256 + threadIdx.x;
    int n = gt >> 6;
    int lane = threadIdx.x & 63;
    if (n >= N_NODES) return;                 // wave-uniform
    int start = (n == 0) ? 0 : offs[n - 1];
    int end = offs[n];
    int deg = end - start;
    if (deg <= 1 || deg > 64) return;         // wave-uniform
    int ke = 0x7fffffff, vs = 0;
    if (lane < deg) { int2 t = eid2[start + lane]; ke = t.x; vs = t.y; }
#pragma unroll
    for (int k = 2; k <= 64; k <<= 1) {
        for (int j = k >> 1; j > 0; j >>= 1) {
            int partner = lane ^ j;
            int ke2 = __shfl(ke, partner, 64);
            int vs2 = __shfl(vs, partner, 64);
            bool up = ((lane & k) == 0);
            bool takemin = ((lane < partner) == up);
            bool sw = takemin ? (ke2 < ke) : (ke2 > ke);
            if (sw) { ke = ke2; vs = vs2; }
        }
    }
    if (lane < deg) eid2[start + lane] = make_int2(ke, vs);
}

// Wave-per-node aggregation, 4 edges in flight, edge list hoisted to regs.
// Uniform trip count (round-8 exec-mask fix) — shuffles with all lanes active.
__global__ __launch_bounds__(256) void agg_kernel(
    const float* __restrict__ x, const float* __restrict__ ea,
    const int2* __restrict__ eid2, const int* __restrict__ offs,
    float* __restrict__ agg)
{
    int gt = blockIdx.x * 256 + threadIdx.x;
    int n = gt >> 6;
    if (n >= N_NODES) return;
    int lane = threadIdx.x & 63;
    int g = lane >> 4, c4 = lane & 15;
    int nu = __builtin_amdgcn_readfirstlane(n);   // SGPR edge-list walk
    int start = (nu == 0) ? 0 : offs[nu - 1];
    int end = offs[nu];
    int deg = end - start;
    int2 my = make_int2(0, 0);
    if (lane < deg) my = eid2[start + lane];      // one load, whole edge list
    float4 acc = make_float4(0.f, 0.f, 0.f, 0.f);
    int dmax = deg < 64 ? deg : 64;
    int iters = (dmax + 3) >> 2;                  // wave-uniform trip count
    for (int j = 0; j < iters; ++j) {
        int k = g + 4 * j;
        int eidx = __shfl(my.x, k, 64);           // all 64 lanes active here
        int sidx = __shfl(my.y, k, 64);
        if (k < dmax) {                           // predicate work only
            float4 e4 = ((const float4*)(ea + (size_t)eidx * HID))[c4];
            float4 x4 = ((const float4*)(x + (size_t)sidx * HID))[c4];
            acc.x += fmaxf(x4.x + e4.x, 0.f);
            acc.y += fmaxf(x4.y + e4.y, 0.f);
            acc.z += fmaxf(x4.z + e4.z, 0.f);
            acc.w += fmaxf(x4.w + e4.w, 0.f);
        }
    }
    for (int i = start + 64 + g; i < end; i += 4) {   // deg>64: never in practice
        int2 p = eid2[i];
        float4 e4 = ((const float4*)(ea + (size_t)p.x * HID))[c4];
        float4 x4 = ((const float4*)(x + (size_t)p.y * HID))[c4];
        acc.x += fmaxf(x4.x + e4.x, 0.f);
        acc.y += fmaxf(x4.y + e4.y, 0.f);
        acc.z += fmaxf(x4.z + e4.z, 0.f);
        acc.w += fmaxf(x4.w + e4.w, 0.f);
    }
    acc.x += __shfl_xor(acc.x, 16, 64);
    acc.y += __shfl_xor(acc.y, 16, 64);
    acc.z += __shfl_xor(acc.z, 16, 64);
    acc.w += __shfl_xor(acc.w, 16, 64);
    acc.x += __shfl_xor(acc.x, 32, 64);
    acc.y += __shfl_xor(acc.y, 32, 64);
    acc.z += __shfl_xor(acc.z, 32, 64);
    acc.w += __shfl_xor(acc.w, 32, 64);
    if (g == 0) ((float4*)(agg + (size_t)n * HID))[c4] = acc;
}

// ===================== MFMA MLP =====================
// Wave handles 16 nodes exactly (100000 = 6250 waves x 16 nodes).
// GEMM form: h = relu(IN @ W1^T + b1); out = h @ W2^T + b2; (relu?); +x.
// mfma_f32_16x16x32_bf16 layouts (guide §3, m89/m91-verified C/D):
//   A[i][k]: i = lane&15,            k = (lane>>4)*8 + b   (b=0..7)
//   B[k][j]: j = lane&15,            k = (lane>>4)*8 + b
//   D[i][j]: j = lane&15 (col),      i = (lane>>4)*4 + reg (row)
// Layer-1 D is in (row=node (g*4+r), col=hidden) layout; layer-2 needs
// A in (row=node lane&15, k=hidden) layout -> 2KB/wave LDS transpose
// (h_lds[node][j], bf16). Wave-private region: no barrier needed, the
// compiler orders ds_write->ds_read via lgkmcnt.
// Replaces the f32 LDS-weights MLP (2048 ds_read_b128/wave, LDS-pipe-bound)
// with 16 MFMA + ~18 LDS ops/wave. bias/relu/residual stay f32.
__global__ __launch_bounds__(256) void mlp_kernel(
    const float* __restrict__ agg,
    const float* __restrict__ W1, const float* __restrict__ b1,
    const float* __restrict__ W2, const float* __restrict__ b2,
    float* __restrict__ x, int last_relu)
{
    __shared__ unsigned short hl[4][16][64];   // [wave][node][hidden] bf16, 8 KB
    int tid = threadIdx.x;
    int wid = tid >> 6, lane = tid & 63;
    int g = lane >> 4, c = lane & 15;
    int m0 = (blockIdx.x * 4 + wid) * 16;      // first node of this wave
    if (m0 >= N_NODES) return;                 // wave-uniform (last block)

    // ---- A-frags: in = agg + x (f32 -> bf16 RNE) ----
    const float* arow = agg + (size_t)(m0 + c) * HID;
    const float* xrow = x + (size_t)(m0 + c) * HID;
    short8 af0, af1;
    {
        int k0 = g * 8;                        // kt = 0
        float4 a0 = *(const float4*)(arow + k0), a1 = *(const float4*)(arow + k0 + 4);
        float4 y0 = *(const float4*)(xrow + k0), y1 = *(const float4*)(xrow + k0 + 4);
        af0 = pack8(make_float4(a0.x + y0.x, a0.y + y0.y, a0.z + y0.z, a0.w + y0.w),
                    make_float4(a1.x + y1.x, a1.y + y1.y, a1.z + y1.z, a1.w + y1.w));
        int k1 = 32 + g * 8;                   // kt = 1
        float4 b0 = *(const float4*)(arow + k1), b1v = *(const float4*)(arow + k1 + 4);
        float4 z0 = *(const float4*)(xrow + k1), z1 = *(const float4*)(xrow + k1 + 4);
        af1 = pack8(make_float4(b0.x + z0.x, b0.y + z0.y, b0.z + z0.z, b0.w + z0.w),
                    make_float4(b1v.x + z1.x, b1v.y + z1.y, b1v.z + z1.z, b1v.w + z1.w));
    }

    // ---- layer 1: 4 j-tiles x 2 k-tiles ----
    f32x4 a10 = {0.f, 0.f, 0.f, 0.f}, a11 = a10, a12 = a10, a13 = a10;
#define L1(JT, ACC) { \
    short8 w0 = ldw(W1, (JT)*16 + c, g * 8); \
    short8 w1 = ldw(W1, (JT)*16 + c, 32 + g * 8); \
    ACC = __builtin_amdgcn_mfma_f32_16x16x32_bf16(af0, w0, ACC, 0, 0, 0); \
    ACC = __builtin_amdgcn_mfma_f32_16x16x32_bf16(af1, w1, ACC, 0, 0, 0); }
    L1(0, a10) L1(1, a11) L1(2, a12) L1(3, a13)
#undef L1

    // ---- bias + relu, store h to LDS in [node][j] layout ----
#define HST(JT, ACC) { float bb = b1[(JT) * 16 + c]; \
    hl[wid][4*g + 0][(JT)*16 + c] = f2bf(fmaxf(ACC[0] + bb, 0.f)); \
    hl[wid][4*g + 1][(JT)*16 + c] = f2bf(fmaxf(ACC[1] + bb, 0.f)); \
    hl[wid][4*g + 2][(JT)*16 + c] = f2bf(fmaxf(ACC[2] + bb, 0.f)); \
    hl[wid][4*g + 3][(JT)*16 + c] = f2bf(fmaxf(ACC[3] + bb, 0.f)); }
    HST(0, a10) HST(1, a11) HST(2, a12) HST(3, a13)
#undef HST

    // ---- layer-2 A-frags from LDS (row = node c, k = hidden) ----
    short8 hf0 = *(const short8*)&hl[wid][c][g * 8];
    short8 hf1 = *(const short8*)&hl[wid][c][32 + g * 8];

    // ---- layer 2: 4 c-tiles x 2 k-tiles ----
    f32x4 a20 = {0.f, 0.f, 0.f, 0.f}, a21 = a20, a22 = a20, a23 = a20;
#define L2(CT, ACC) { \
    short8 w0 = ldw(W2, (CT)*16 + c, g * 8); \
    short8 w1 = ldw(W2, (CT)*16 + c, 32 + g * 8); \
    ACC = __builtin_amdgcn_mfma_f32_16x16x32_bf16(hf0, w0, ACC, 0, 0, 0); \
    ACC = __builtin_amdgcn_mfma_f32_16x16x32_bf16(hf1, w1, ACC, 0, 0, 0); }
    L2(0, a20) L2(1, a21) L2(2, a22) L2(3, a23)
#undef L2

    // ---- epilogue: +b2, (relu?), +x residual, store (all f32) ----
#define EPI(CT, ACC) { float bb = b2[(CT) * 16 + c]; \
    _Pragma("unroll") \
    for (int r = 0; r < 4; ++r) { \
        size_t idx = (size_t)(m0 + 4*g + r) * HID + (CT) * 16 + c; \
        float o = ACC[r] + bb; \
        if (last_relu) o = fmaxf(o, 0.f); \
        x[idx] = o + x[idx]; } }
    EPI(0, a20) EPI(1, a21) EPI(2, a22) EPI(3, a23)
#undef EPI
}

extern "C" void kernel_launch(void* const* d_in, const int* in_sizes, int n_in,
                              void* d_out, int out_size, void* d_ws, size_t ws_size,
                              hipStream_t stream) {
    const float* node_emb = (const float*)d_in[0];
    const float* W1 = (const float*)d_in[1];
    const float* b1 = (const float*)d_in[2];
    const float* W2 = (const float*)d_in[3];
    const float* b2 = (const float*)d_in[4];
    const float* ea = (const float*)d_in[5];
    const int* z = (const int*)d_in[6];
    const int* ei = (const int*)d_in[7];
    const int* src = ei;            // edge_index[0] = message sender
    const int* dst = ei + N_EDGES;  // edge_index[1] = aggregation target

    float* x = (float*)d_out;                       // node features live here
    float* agg = (float*)d_ws;                               // 25.6 MB
    int2* eid2 = (int2*)(agg + (size_t)N_NODES * HID);       // 8 MB
    int* offs = (int*)(eid2 + N_EDGES);                      // 0.4 MB
    int* bsum = offs + N_NODES;                              // 98 ints (pad 128)

    const int eb = (N_EDGES + 255) / 256;             // 3907
    const int nodewave_blocks = (N_NODES * 64) / 256; // 25000
    const int mlp_blocks = (N_NODES / 16 + 3) / 4;    // 1563 (6250 waves)

    // ---- CSR build (once, reused by all 3 convs) ----
    hipMemsetAsync(offs, 0, N_NODES * sizeof(int), stream);
    prep_kernel<<<GATHER_BLOCKS + HIST_BLOCKS, 256, 0, stream>>>(
        node_emb, z, x, dst, offs);
    scan1_kernel<<<SCAN_NB, SCAN_B, 0, stream>>>(offs, bsum);
    scan2_kernel<<<1, 128, 0, stream>>>(bsum);
    scan3_kernel<<<SCAN_NB, SCAN_B, 0, stream>>>(offs, bsum);
    fill_kernel<<<eb, 256, 0, stream>>>(src, dst, offs, eid2);
    sort_kernel<<<nodewave_blocks, 256, 0, stream>>>(offs, eid2);

    // ---- 3 convs, x updated in place in d_out ----
    for (int conv = 0; conv < 3; ++conv) {
        agg_kernel<<<nodewave_blocks, 256, 0, stream>>>(x, ea, eid2, offs, agg);
        mlp_kernel<<<mlp_blocks, 256, 0, stream>>>(
            agg, W1 + conv * HID * HID, b1 + conv * HID,
            W2 + conv * HID * HID, b2 + conv * HID,
            x, conv < 2 ? 1 : 0);
    }
}